// Round 9
// baseline (366.325 us; speedup 1.0000x reference)
//
#include <hip/hip_runtime.h>
#include <stdint.h>

#define NL  16
#define NE  16384           // entries per level (power of two)
#define BLK 512             // threads per block == points per block

constexpr int kRes[NL] = {16,20,25,32,40,50,64,80,101,128,161,203,256,322,406,512};

// ---------------- pre-pass: pack emb (L,2,NE) fp32 -> (L,NE) u32 of 2x bf16 ----------------
__global__ void pack_kernel(const float* __restrict__ emb, uint32_t* __restrict__ tbl) {
    int i = blockIdx.x * blockDim.x + threadIdx.x;     // 0 .. NL*NE-1
    if (i >= NL * NE) return;
    int l = i >> 14;
    int j = i & (NE - 1);
    float e0 = emb[(size_t)l * 2 * NE + j];
    float e1 = emb[(size_t)l * 2 * NE + NE + j];
    uint32_t u0 = __float_as_uint(e0); u0 = (u0 + 0x7fffu + ((u0 >> 16) & 1u)) >> 16;  // RTNE bf16
    uint32_t u1 = __float_as_uint(e1); u1 = (u1 + 0x7fffu + ((u1 >> 16) & 1u)) >> 16;
    tbl[i] = u0 | (u1 << 16);
}

// ---- main: BLK=512, 1 pt/thread, single 64-KB buffer, TWO co-resident blocks/CU.
// HW model (R1..R8): waves/SIMD = floor(256 / VGPR64) -> VGPR=64 gives 4 waves/SIMD
// = 16 waves/CU. A 1024-thread block monopolizes that; two 512-thread blocks fit the
// same budget with independent barrier domains (R4 showed 47% occupancy at 2x512).
// Staging split: half-table prefetched into 16 regs during gathers; second half
// load+write-through after barrier B (partner block hides the exposed latency).
__global__ __launch_bounds__(BLK, 4)   // 256/4 = 64-VGPR budget; cap 4 waves/SIMD
void hashenc_kernel(const float* __restrict__ x, const uint32_t* __restrict__ tbl,
                    float* __restrict__ out) {
    __shared__ __align__(16) uint32_t lds[NE];         // 64 KB single buffer

    const int tid  = threadIdx.x;
    const size_t b = (size_t)blockIdx.x * BLK + tid;

    const float3 p3 = ((const float3*)x)[b];
    const float pc[3] = {p3.x, p3.y, p3.z};

    // prologue: stage level 0 (512 threads x 8 passes x 16 B = 64 KB), write-through
    {
        const uint4* g = (const uint4*)tbl;
        uint4* dst = (uint4*)lds;
        #pragma unroll
        for (int p = 0; p < 8; ++p) dst[p * BLK + tid] = g[p * BLK + tid];
    }

    uint32_t accp[8];                                  // 8 levels x packed bf16x2 (f0|f1)

    #pragma unroll
    for (int l = 0; l < NL; ++l) {
        __syncthreads();   // barrier A: staged table for level l visible

        // prefetch FIRST HALF (32 KB) of next level's table; 16 regs live through gathers
        uint4 rA0, rA1, rA2, rA3;
        if (l + 1 < NL) {
            const uint4* g = (const uint4*)(tbl + ((size_t)(l + 1) << 14));
            rA0 = g[0 * BLK + tid];
            rA1 = g[1 * BLK + tid];
            rA2 = g[2 * BLK + tid];
            rA3 = g[3 * BLK + tid];
        }

        const int   res  = kRes[l];
        const float hres = 0.5f * (float)res;          // unnorm: ix = p*hres + (hres-0.5)
        const float cadd = hres - 0.5f;
        const bool hashed = (res * res * res > NE);

        // grid_sample align_corners=False unnormalization (1 fma per dim)
        float fr[3]; int c0[3];
        #pragma unroll
        for (int d = 0; d < 3; ++d) {
            float ix = fmaf(pc[d], hres, cadd);
            float fl = floorf(ix);
            fr[d] = ix - fl;
            c0[d] = (int)fl;                           // in [-1, res-1]
        }

        // per-dim validity-folded weights + index contributions
        float    w[3][2];
        uint32_t a[3][2];
        #pragma unroll
        for (int d = 0; d < 3; ++d) {
            const int lo = c0[d], hi = c0[d] + 1;
            w[d][0] = (lo >= 0)     ? (1.0f - fr[d]) : 0.0f;   // zero-padding
            w[d][1] = (hi <= res-1) ? fr[d]          : 0.0f;
            const int loc = lo < 0 ? 0 : lo;
            const int hic = hi > res - 1 ? res - 1 : hi;
            if (hashed) {
                constexpr uint32_t P[3] = {1u, 2654435761u, 805459861u};
                a[d][0] = (uint32_t)loc * P[d];
                a[d][1] = (uint32_t)hic * P[d];
            } else {
                const uint32_t stride = (d == 0) ? 1u : ((d == 1) ? (uint32_t)res
                                                                  : (uint32_t)(res * res));
                a[d][0] = (uint32_t)loc * stride;
                a[d][1] = (uint32_t)hic * stride;
            }
        }

        // pairwise-factored xy terms (12 ops instead of 16)
        float    wxy[4];
        uint32_t axy[4];
        #pragma unroll
        for (int c = 0; c < 4; ++c) {
            const int bx = c & 1, by = (c >> 1) & 1;
            wxy[c] = w[0][bx] * w[1][by];
            axy[c] = hashed ? (a[0][bx] ^ a[1][by]) : (a[0][bx] + a[1][by]);
        }

        float f0 = 0.0f, f1 = 0.0f;
        #pragma unroll
        for (int c = 0; c < 8; ++c) {
            const int cxy = c & 3, bz = (c >> 2) & 1;
            const uint32_t idx = hashed
                ? ((axy[cxy] ^ a[2][bz]) & (uint32_t)(NE - 1))
                : (axy[cxy] + a[2][bz]);
            const float wt = wxy[cxy] * w[2][bz];
            const uint32_t v = lds[idx];
            f0 = fmaf(wt, __uint_as_float(v << 16),          f0);  // dim 0 (low bf16)
            f1 = fmaf(wt, __uint_as_float(v & 0xffff0000u),  f1);  // dim 1 (high bf16)
        }

        // pack level result to bf16x2 (round-to-nearest-up, <=0.5 ulp; validated R2)
        {
            const uint32_t u0 = (__float_as_uint(f0) + 0x8000u) >> 16;
            const uint32_t u1 = (__float_as_uint(f1) + 0x8000u) & 0xffff0000u;
            accp[l & 7] = u0 | u1;
        }

        // barrier B: all gathers of level l done -> safe to overwrite buffer
        if (l + 1 < NL) {
            __syncthreads();
            uint4* dst = (uint4*)lds;
            dst[0 * BLK + tid] = rA0;                  // first half: prefetched regs
            dst[1 * BLK + tid] = rA1;
            dst[2 * BLK + tid] = rA2;
            dst[3 * BLK + tid] = rA3;
            const uint4* g = (const uint4*)(tbl + ((size_t)(l + 1) << 14));
            #pragma unroll
            for (int p = 4; p < 8; ++p)                // second half: write-through
                dst[p * BLK + tid] = g[p * BLK + tid]; // (partner block hides latency)
        }

        // flush one 64-B half-line per point per 8-level group
        if ((l & 7) == 7) {
            float4* o = (float4*)(out + b * 32 + (size_t)(l >> 3) * 16);
            #pragma unroll
            for (int q = 0; q < 4; ++q) {
                const uint32_t v0 = accp[2 * q], v1 = accp[2 * q + 1];
                o[q] = make_float4(__uint_as_float(v0 << 16),
                                   __uint_as_float(v0 & 0xffff0000u),
                                   __uint_as_float(v1 << 16),
                                   __uint_as_float(v1 & 0xffff0000u));
            }
        }
    }
}

extern "C" void kernel_launch(void* const* d_in, const int* in_sizes, int n_in,
                              void* d_out, int out_size, void* d_ws, size_t ws_size,
                              hipStream_t stream) {
    const float* x   = (const float*)d_in[0];   // (B,3) fp32
    const float* emb = (const float*)d_in[1];   // (16,2,16384) fp32
    uint32_t* tbl = (uint32_t*)d_ws;            // (16,16384) packed bf16x2 = 1 MB
    float* out = (float*)d_out;                 // (B,16,2) fp32

    const int npack = NL * NE;
    pack_kernel<<<dim3((npack + 255) / 256), dim3(256), 0, stream>>>(emb, tbl);

    const int nblocks = (1 << 21) / BLK;        // 4096 blocks of 512 points
    hashenc_kernel<<<dim3(nblocks), dim3(BLK), 0, stream>>>(x, tbl, out);
}

// Round 10
// 275.297 us; speedup vs baseline: 1.3307x; 1.3307x over previous
//
#include <hip/hip_runtime.h>
#include <stdint.h>

#define NL  16
#define NE  16384               // entries per level (power of two)
#define NB  32                  // chunks (blocks) per level in pass 1
#define BLK1 512                // pass-1 threads per block
#define PPB  ((1 << 21) / NB)   // 65536 points per pass-1 block
#define ITER (PPB / BLK1)       // 128 points per thread
#define BLK2 256                // pass-2 threads per block
#define BLKF 1024               // fallback threads per block

constexpr int kRes[NL] = {16,20,25,32,40,50,64,80,101,128,161,203,256,322,406,512};
__device__ const int dRes[NL] = {16,20,25,32,40,50,64,80,101,128,161,203,256,322,406,512};

// ---------------- pre-pass: pack emb (L,2,NE) fp32 -> (L,NE) u32 of 2x bf16 ----------------
__global__ void pack_kernel(const float* __restrict__ emb, uint32_t* __restrict__ tbl) {
    int i = blockIdx.x * blockDim.x + threadIdx.x;     // 0 .. NL*NE-1
    if (i >= NL * NE) return;
    int l = i >> 14;
    int j = i & (NE - 1);
    float e0 = emb[(size_t)l * 2 * NE + j];
    float e1 = emb[(size_t)l * 2 * NE + NE + j];
    uint32_t u0 = __float_as_uint(e0); u0 = (u0 + 0x7fffu + ((u0 >> 16) & 1u)) >> 16;  // RTNE bf16
    uint32_t u1 = __float_as_uint(e1); u1 = (u1 + 0x7fffu + ((u1 >> 16) & 1u)) >> 16;
    tbl[i] = u0 | (u1 << 16);
}

// ---------------- pass 1: LEVEL-MAJOR. One block = one level x 65536 points. ----------------
// Table staged ONCE per block (3% of LDS traffic vs 50% in the point-major scheme), then a
// barrier-free gather loop: waves free-run, VALU/LDS overlap instead of lockstep bursts.
// 512 blocks = 2/CU (128 KB LDS, 16 waves at VGPR<=64 -- co-residency proven in R9).
// Output: packed bf16x2 to (L,B) u32 intermediate, fully coalesced (transposed in pass 2).
__global__ __launch_bounds__(BLK1, 4)   // 64-VGPR budget (proven no-spill at this shape)
void level_kernel(const float* __restrict__ x, const uint32_t* __restrict__ tbl,
                  uint32_t* __restrict__ mid) {
    __shared__ __align__(16) uint32_t lds[NE];         // 64 KB: this level's full table

    const int tid   = threadIdx.x;
    const int level = blockIdx.x >> 5;                 // 32 chunks per level
    const int chunk = blockIdx.x & (NB - 1);

    // stage this level's table once (512 thr x 8 x 16 B = 64 KB)
    {
        const uint4* g = (const uint4*)(tbl + ((size_t)level << 14));
        uint4* dst = (uint4*)lds;
        #pragma unroll
        for (int p = 0; p < 8; ++p) dst[p * BLK1 + tid] = g[p * BLK1 + tid];
    }
    __syncthreads();                                   // only barrier in the kernel

    const int   res  = dRes[level];
    const float hres = 0.5f * (float)res;              // unnorm: ix = p*hres + (hres-0.5)
    const float cadd = hres - 0.5f;
    const bool hashed = (res * res * res > NE);
    const uint32_t sy = (uint32_t)res, sz = (uint32_t)(res * res);

    uint32_t* dst = mid + ((size_t)level << 21);
    const size_t pbase = (size_t)chunk * PPB + tid;

    for (int i = 0; i < ITER; ++i) {
        const size_t p = pbase + (size_t)i * BLK1;
        const float3 pt = ((const float3*)x)[p];
        const float pc[3] = {pt.x, pt.y, pt.z};

        // grid_sample align_corners=False unnormalization (1 fma per dim)
        float fr[3]; int c0[3];
        #pragma unroll
        for (int d = 0; d < 3; ++d) {
            float ix = fmaf(pc[d], hres, cadd);
            float fl = floorf(ix);
            fr[d] = ix - fl;
            c0[d] = (int)fl;                           // in [-1, res-1]
        }

        // per-dim validity-folded weights + index contributions
        float    w[3][2];
        uint32_t a[3][2];
        #pragma unroll
        for (int d = 0; d < 3; ++d) {
            const int lo = c0[d], hi = c0[d] + 1;
            w[d][0] = (lo >= 0)     ? (1.0f - fr[d]) : 0.0f;   // zero-padding
            w[d][1] = (hi <= res-1) ? fr[d]          : 0.0f;
            const int loc = lo < 0 ? 0 : lo;
            const int hic = hi > res - 1 ? res - 1 : hi;
            if (hashed) {
                constexpr uint32_t P[3] = {1u, 2654435761u, 805459861u};
                a[d][0] = (uint32_t)loc * P[d];
                a[d][1] = (uint32_t)hic * P[d];
            } else {
                const uint32_t stride = (d == 0) ? 1u : ((d == 1) ? sy : sz);
                a[d][0] = (uint32_t)loc * stride;
                a[d][1] = (uint32_t)hic * stride;
            }
        }

        // pairwise-factored xy terms
        float    wxy[4];
        uint32_t axy[4];
        #pragma unroll
        for (int c = 0; c < 4; ++c) {
            const int bx = c & 1, by = (c >> 1) & 1;
            wxy[c] = w[0][bx] * w[1][by];
            axy[c] = hashed ? (a[0][bx] ^ a[1][by]) : (a[0][bx] + a[1][by]);
        }

        float f0 = 0.0f, f1 = 0.0f;
        #pragma unroll
        for (int c = 0; c < 8; ++c) {
            const int cxy = c & 3, bz = (c >> 2) & 1;
            const uint32_t idx = hashed
                ? ((axy[cxy] ^ a[2][bz]) & (uint32_t)(NE - 1))
                : (axy[cxy] + a[2][bz]);
            const float wt = wxy[cxy] * w[2][bz];
            const uint32_t v = lds[idx];
            f0 = fmaf(wt, __uint_as_float(v << 16),          f0);  // dim 0 (low bf16)
            f1 = fmaf(wt, __uint_as_float(v & 0xffff0000u),  f1);  // dim 1 (high bf16)
        }

        // pack to bf16x2 (round-to-nearest-up, <=0.5 ulp; validated R2/R8) -> coalesced store
        const uint32_t u0 = (__float_as_uint(f0) + 0x8000u) >> 16;
        const uint32_t u1 = (__float_as_uint(f1) + 0x8000u) & 0xffff0000u;
        dst[p] = u0 | u1;
    }
}

// ---------------- pass 2: transpose (L,B) u32 -> (B,L,2) fp32, full-line writes ----------------
__global__ __launch_bounds__(BLK2, 4)
void transpose_kernel(const uint32_t* __restrict__ mid, float* __restrict__ out) {
    const size_t p = (size_t)blockIdx.x * BLK2 + threadIdx.x;
    uint32_t v[NL];
    #pragma unroll
    for (int l = 0; l < NL; ++l) v[l] = mid[((size_t)l << 21) + p];   // 16 coalesced streams
    float4* o = (float4*)(out + p * 32);                              // one 128-B line/point
    #pragma unroll
    for (int q = 0; q < 8; ++q) {
        const uint32_t v0 = v[2 * q], v1 = v[2 * q + 1];
        o[q] = make_float4(__uint_as_float(v0 << 16), __uint_as_float(v0 & 0xffff0000u),
                           __uint_as_float(v1 << 16), __uint_as_float(v1 & 0xffff0000u));
    }
}

// ---------------- fallback: R6 point-major kernel (proven 230 us) if ws too small ----------------
__global__ __launch_bounds__(BLKF, 4)
void hashenc_kernel(const float* __restrict__ x, const uint32_t* __restrict__ tbl,
                    float* __restrict__ out) {
    __shared__ __align__(16) uint32_t lds[NE];

    const int tid  = threadIdx.x;
    const size_t b = (size_t)blockIdx.x * BLKF + tid;

    const float3 p3 = ((const float3*)x)[b];
    const float pc[3] = {p3.x, p3.y, p3.z};

    {
        const uint4* g = (const uint4*)tbl;
        uint4 r0 = g[0 * BLKF + tid], r1 = g[1 * BLKF + tid];
        uint4 r2 = g[2 * BLKF + tid], r3 = g[3 * BLKF + tid];
        uint4* dst = (uint4*)lds;
        dst[0 * BLKF + tid] = r0; dst[1 * BLKF + tid] = r1;
        dst[2 * BLKF + tid] = r2; dst[3 * BLKF + tid] = r3;
    }

    float acc[16];
    #pragma unroll
    for (int i = 0; i < 16; ++i) acc[i] = 0.0f;

    #pragma unroll
    for (int l = 0; l < NL; ++l) {
        __syncthreads();

        uint4 r0, r1, r2, r3;
        if (l + 1 < NL) {
            const uint4* g = (const uint4*)(tbl + ((size_t)(l + 1) << 14));
            r0 = g[0 * BLKF + tid]; r1 = g[1 * BLKF + tid];
            r2 = g[2 * BLKF + tid]; r3 = g[3 * BLKF + tid];
        }

        const int   res  = kRes[l];
        const float hres = 0.5f * (float)res;
        const float cadd = hres - 0.5f;
        const bool hashed = (res * res * res > NE);

        float fr[3]; int c0[3];
        #pragma unroll
        for (int d = 0; d < 3; ++d) {
            float ix = fmaf(pc[d], hres, cadd);
            float fl = floorf(ix);
            fr[d] = ix - fl;
            c0[d] = (int)fl;
        }

        float    w[3][2];
        uint32_t a[3][2];
        #pragma unroll
        for (int d = 0; d < 3; ++d) {
            const int lo = c0[d], hi = c0[d] + 1;
            w[d][0] = (lo >= 0)     ? (1.0f - fr[d]) : 0.0f;
            w[d][1] = (hi <= res-1) ? fr[d]          : 0.0f;
            const int loc = lo < 0 ? 0 : lo;
            const int hic = hi > res - 1 ? res - 1 : hi;
            if (hashed) {
                constexpr uint32_t P[3] = {1u, 2654435761u, 805459861u};
                a[d][0] = (uint32_t)loc * P[d];
                a[d][1] = (uint32_t)hic * P[d];
            } else {
                const uint32_t stride = (d == 0) ? 1u : ((d == 1) ? (uint32_t)res
                                                                  : (uint32_t)(res * res));
                a[d][0] = (uint32_t)loc * stride;
                a[d][1] = (uint32_t)hic * stride;
            }
        }

        float    wxy[4];
        uint32_t axy[4];
        #pragma unroll
        for (int c = 0; c < 4; ++c) {
            const int bx = c & 1, by = (c >> 1) & 1;
            wxy[c] = w[0][bx] * w[1][by];
            axy[c] = hashed ? (a[0][bx] ^ a[1][by]) : (a[0][bx] + a[1][by]);
        }

        float f0 = 0.0f, f1 = 0.0f;
        #pragma unroll
        for (int c = 0; c < 8; ++c) {
            const int cxy = c & 3, bz = (c >> 2) & 1;
            const uint32_t idx = hashed
                ? ((axy[cxy] ^ a[2][bz]) & (uint32_t)(NE - 1))
                : (axy[cxy] + a[2][bz]);
            const float wt = wxy[cxy] * w[2][bz];
            const uint32_t v = lds[idx];
            f0 = fmaf(wt, __uint_as_float(v << 16),          f0);
            f1 = fmaf(wt, __uint_as_float(v & 0xffff0000u),  f1);
        }
        acc[2 * (l & 7) + 0] = f0;
        acc[2 * (l & 7) + 1] = f1;

        if (l + 1 < NL) {
            __syncthreads();
            uint4* dst = (uint4*)lds;
            dst[0 * BLKF + tid] = r0; dst[1 * BLKF + tid] = r1;
            dst[2 * BLKF + tid] = r2; dst[3 * BLKF + tid] = r3;
        }

        if ((l & 7) == 7) {
            float4* o = (float4*)(out + b * 32 + (size_t)(l >> 3) * 16);
            o[0] = make_float4(acc[0],  acc[1],  acc[2],  acc[3]);
            o[1] = make_float4(acc[4],  acc[5],  acc[6],  acc[7]);
            o[2] = make_float4(acc[8],  acc[9],  acc[10], acc[11]);
            o[3] = make_float4(acc[12], acc[13], acc[14], acc[15]);
        }
    }
}

extern "C" void kernel_launch(void* const* d_in, const int* in_sizes, int n_in,
                              void* d_out, int out_size, void* d_ws, size_t ws_size,
                              hipStream_t stream) {
    const float* x   = (const float*)d_in[0];   // (B,3) fp32
    const float* emb = (const float*)d_in[1];   // (16,2,16384) fp32
    float* out = (float*)d_out;                 // (B,16,2) fp32

    uint32_t* tbl = (uint32_t*)d_ws;            // (16,16384) packed bf16x2 = 1 MB
    const size_t tbl_bytes = (size_t)NL * NE * 4;
    const size_t mid_bytes = (size_t)NL * (1 << 21) * 4;   // 128 MB intermediate

    const int npack = NL * NE;
    pack_kernel<<<dim3((npack + 255) / 256), dim3(256), 0, stream>>>(emb, tbl);

    if (ws_size >= tbl_bytes + mid_bytes) {
        uint32_t* mid = tbl + (size_t)NL * NE;
        level_kernel<<<dim3(NL * NB), dim3(BLK1), 0, stream>>>(x, tbl, mid);
        transpose_kernel<<<dim3((1 << 21) / BLK2), dim3(BLK2), 0, stream>>>(mid, out);
    } else {
        hashenc_kernel<<<dim3((1 << 21) / BLKF), dim3(BLKF), 0, stream>>>(x, tbl, out);
    }
}